// Round 3
// baseline (593.628 us; speedup 1.0000x reference)
//
#include <hip/hip_runtime.h>
#include <math.h>

#define H 1024
#define S 32768
#define NB3 2048                    // scores kernel blocks (4 waves, 16 rows each)

__device__ __forceinline__ float wave_reduce_sum(float v) {
    #pragma unroll
    for (int off = 32; off > 0; off >>= 1) v += __shfl_xor(v, off, 64);
    return v;
}

// y[row] = dot(W[row,:], x) + b[row].  One wave per row, 4 rows per block.
// Also zeroes *counter from block 0 (ws arrives poisoned 0xAA).
__global__ __launch_bounds__(256) void gemv_kernel(const float* __restrict__ W,
                                                   const float* __restrict__ x,
                                                   const float* __restrict__ b,
                                                   float* __restrict__ y,
                                                   unsigned int* counter) {
    __shared__ float xs[H];
    const int tid = threadIdx.x;
    if (counter && blockIdx.x == 0 && tid == 0) *counter = 0u;
    reinterpret_cast<float4*>(xs)[tid] = reinterpret_cast<const float4*>(x)[tid];
    __syncthreads();

    const int wave = tid >> 6, lane = tid & 63;
    const int row = blockIdx.x * 4 + wave;
    const float4* Wr  = reinterpret_cast<const float4*>(W + (size_t)row * H);
    const float4* xs4 = reinterpret_cast<const float4*>(xs);

    float acc = 0.f;
    #pragma unroll
    for (int k = 0; k < 4; ++k) {
        const float4 w = Wr[k * 64 + lane];
        const float4 e = xs4[k * 64 + lane];
        acc += w.x * e.x + w.y * e.y + w.z * e.z + w.w * e.w;
    }
    acc = wave_reduce_sum(acc);
    if (lane == 0) y[row] = acc + b[row];
}

// scores + full softmax via last-block finalize.
__global__ __launch_bounds__(256) void scores_softmax_kernel(
    const float* __restrict__ enc,
    const float* __restrict__ energy,
    float* __restrict__ scores,      // [S]   ws
    float* __restrict__ blockmax,    // [NB3] ws
    float* __restrict__ blocksum,    // [NB3] ws
    unsigned int* __restrict__ counter,
    float* __restrict__ out)         // [S]
{
    __shared__ float es[H];
    __shared__ float redm[4], reds[4];
    __shared__ unsigned int isLast;

    const int tid = threadIdx.x;
    reinterpret_cast<float4*>(es)[tid] = reinterpret_cast<const float4*>(energy)[tid];
    __syncthreads();

    const int wave = tid >> 6, lane = tid & 63;
    const int bid  = blockIdx.x;
    const float4* es4 = reinterpret_cast<const float4*>(es);

    // ---- scores: 4 rows per wave, contiguous ----
    const int wrow0 = (bid * 4 + wave) * 4;
    float sc[4];
    float wmax = -INFINITY;
    #pragma unroll
    for (int p = 0; p < 4; ++p) {
        const float4* Er = reinterpret_cast<const float4*>(enc + (size_t)(wrow0 + p) * H);
        float acc = 0.f;
        #pragma unroll
        for (int k = 0; k < 4; ++k) {
            const float4 w = Er[k * 64 + lane];
            const float4 e = es4[k * 64 + lane];
            acc += w.x * e.x + w.y * e.y + w.z * e.z + w.w * e.w;
        }
        acc = wave_reduce_sum(acc);          // all lanes hold the score
        sc[p] = acc;
        wmax = fmaxf(wmax, acc);
    }
    if (lane == 0) {
        reinterpret_cast<float4*>(scores)[bid * 4 + wave] =
            make_float4(sc[0], sc[1], sc[2], sc[3]);
        redm[wave] = wmax;
    }
    __syncthreads();
    const float bm = fmaxf(fmaxf(redm[0], redm[1]), fmaxf(redm[2], redm[3]));

    float wsum = 0.f;                        // wave-uniform
    #pragma unroll
    for (int p = 0; p < 4; ++p) wsum += expf(sc[p] - bm);
    if (lane == 0) reds[wave] = wsum;
    __syncthreads();
    if (tid == 0) {
        blockmax[bid] = bm;
        blocksum[bid] = reds[0] + reds[1] + reds[2] + reds[3];
    }

    // ---- last-block handoff ----
    __threadfence();
    if (tid == 0) isLast = (atomicAdd(counter, 1u) == (unsigned)(gridDim.x - 1));
    __syncthreads();
    if (!isLast) return;
    __threadfence();

    // ---- finalize (single block): global max, total, normalize ----
    __shared__ float fred[256];
    float m = -INFINITY;
    #pragma unroll
    for (int i = 0; i < NB3 / 256; ++i) m = fmaxf(m, blockmax[tid + i * 256]);
    fred[tid] = m;
    __syncthreads();
    for (int s = 128; s > 0; s >>= 1) {
        if (tid < s) fred[tid] = fmaxf(fred[tid], fred[tid + s]);
        __syncthreads();
    }
    const float M = fred[0];
    __syncthreads();

    float t = 0.f;
    #pragma unroll
    for (int i = 0; i < NB3 / 256; ++i) {
        const int b = tid + i * 256;
        t += blocksum[b] * expf(blockmax[b] - M);
    }
    fred[tid] = t;
    __syncthreads();
    for (int s = 128; s > 0; s >>= 1) {
        if (tid < s) fred[tid] += fred[tid + s];
        __syncthreads();
    }
    const float inv = 1.0f / fred[0];

    const float4* s4 = reinterpret_cast<const float4*>(scores);
    float4* o4 = reinterpret_cast<float4*>(out);
    for (int i = tid; i < S / 4; i += 256) {
        const float4 v = s4[i];
        o4[i] = make_float4(expf(v.x - M) * inv, expf(v.y - M) * inv,
                            expf(v.z - M) * inv, expf(v.w - M) * inv);
    }
}

extern "C" void kernel_launch(void* const* d_in, const int* in_sizes, int n_in,
                              void* d_out, int out_size, void* d_ws, size_t ws_size,
                              hipStream_t stream) {
    const float* hidden = (const float*)d_in[0];
    const float* enc    = (const float*)d_in[1];
    const float* W_lin  = (const float*)d_in[2];
    const float* b_lin  = (const float*)d_in[3];
    const float* W_attn = (const float*)d_in[4];
    const float* b_attn = (const float*)d_in[5];
    float* out = (float*)d_out;
    float* ws  = (float*)d_ws;

    float* scores   = ws;                        // 32768
    float* blockmax = ws + S;                    // 2048
    float* blocksum = ws + S + NB3;              // 2048
    float* h        = ws + S + 2 * NB3;          // 1024
    float* energy   = ws + S + 2 * NB3 + H;      // 1024
    unsigned int* counter = (unsigned int*)(ws + S + 2 * NB3 + 2 * H);

    // K1 zeroes the counter (block 0) before K3 runs; stream order guarantees visibility.
    gemv_kernel<<<H / 4, 256, 0, stream>>>(W_lin, hidden, b_lin, h, counter);
    gemv_kernel<<<H / 4, 256, 0, stream>>>(W_attn, h, b_attn, energy, nullptr);
    scores_softmax_kernel<<<NB3, 256, 0, stream>>>(enc, energy, scores, blockmax,
                                                   blocksum, counter, out);
}

// Round 4
// 212.918 us; speedup vs baseline: 2.7881x; 2.7881x over previous
//
#include <hip/hip_runtime.h>
#include <math.h>

#define H 1024
#define S 32768
#define NB3 2048                    // scores kernel blocks (4 waves, 4 rows/wave)

__device__ __forceinline__ float wave_reduce_sum(float v) {
    #pragma unroll
    for (int off = 32; off > 0; off >>= 1) v += __shfl_xor(v, off, 64);
    return v;
}

// y[row] = dot(W[row,:], x) + b[row].  One wave per row, 4 rows per block.
__global__ __launch_bounds__(256) void gemv_kernel(const float* __restrict__ W,
                                                   const float* __restrict__ x,
                                                   const float* __restrict__ b,
                                                   float* __restrict__ y) {
    __shared__ float xs[H];
    const int tid = threadIdx.x;
    reinterpret_cast<float4*>(xs)[tid] = reinterpret_cast<const float4*>(x)[tid];
    __syncthreads();

    const int wave = tid >> 6, lane = tid & 63;
    const int row = blockIdx.x * 4 + wave;
    const float4* Wr  = reinterpret_cast<const float4*>(W + (size_t)row * H);
    const float4* xs4 = reinterpret_cast<const float4*>(xs);

    float acc = 0.f;
    #pragma unroll
    for (int k = 0; k < 4; ++k) {
        const float4 w = Wr[k * 64 + lane];
        const float4 e = xs4[k * 64 + lane];
        acc += w.x * e.x + w.y * e.y + w.z * e.z + w.w * e.w;
    }
    acc = wave_reduce_sum(acc);
    if (lane == 0) y[row] = acc + b[row];
}

// scores[row] = enc[row,:] . energy, plus per-block max and local exp-sum.
// NO fences / atomics — visibility via kernel boundary.
__global__ __launch_bounds__(256) void scores_kernel(
    const float* __restrict__ enc,
    const float* __restrict__ energy,
    float* __restrict__ scores,      // [S]   ws
    float* __restrict__ blockmax,    // [NB3] ws
    float* __restrict__ blocksum)    // [NB3] ws
{
    __shared__ float es[H];
    __shared__ float redm[4], reds[4];

    const int tid = threadIdx.x;
    reinterpret_cast<float4*>(es)[tid] = reinterpret_cast<const float4*>(energy)[tid];
    __syncthreads();

    const int wave = tid >> 6, lane = tid & 63;
    const int bid  = blockIdx.x;
    const float4* es4 = reinterpret_cast<const float4*>(es);

    const int wrow0 = (bid * 4 + wave) * 4;
    float sc[4];
    float wmax = -INFINITY;
    #pragma unroll
    for (int p = 0; p < 4; ++p) {
        const float4* Er = reinterpret_cast<const float4*>(enc + (size_t)(wrow0 + p) * H);
        float acc = 0.f;
        #pragma unroll
        for (int k = 0; k < 4; ++k) {
            const float4 w = Er[k * 64 + lane];
            const float4 e = es4[k * 64 + lane];
            acc += w.x * e.x + w.y * e.y + w.z * e.z + w.w * e.w;
        }
        acc = wave_reduce_sum(acc);          // all lanes hold the score
        sc[p] = acc;
        wmax = fmaxf(wmax, acc);
    }
    if (lane == 0) {
        reinterpret_cast<float4*>(scores)[bid * 4 + wave] =
            make_float4(sc[0], sc[1], sc[2], sc[3]);
        redm[wave] = wmax;
    }
    __syncthreads();
    const float bm = fmaxf(fmaxf(redm[0], redm[1]), fmaxf(redm[2], redm[3]));

    float wsum = 0.f;                        // wave-uniform (sc is wave-uniform)
    #pragma unroll
    for (int p = 0; p < 4; ++p) wsum += expf(sc[p] - bm);
    if (lane == 0) reds[wave] = wsum;
    __syncthreads();
    if (tid == 0) {
        blockmax[bid] = bm;
        blocksum[bid] = reds[0] + reds[1] + reds[2] + reds[3];
    }
}

// Single block: global max, rescaled total, normalize all S elements.
__global__ __launch_bounds__(1024) void finalize_kernel(
    const float* __restrict__ scores,
    const float* __restrict__ blockmax,
    const float* __restrict__ blocksum,
    float* __restrict__ out)
{
    __shared__ float red[1024];
    const int tid = threadIdx.x;

    float m = fmaxf(blockmax[tid], blockmax[tid + 1024]);
    red[tid] = m;
    __syncthreads();
    for (int s = 512; s > 0; s >>= 1) {
        if (tid < s) red[tid] = fmaxf(red[tid], red[tid + s]);
        __syncthreads();
    }
    const float M = red[0];
    __syncthreads();

    float t = blocksum[tid] * expf(blockmax[tid] - M)
            + blocksum[tid + 1024] * expf(blockmax[tid + 1024] - M);
    red[tid] = t;
    __syncthreads();
    for (int s = 512; s > 0; s >>= 1) {
        if (tid < s) red[tid] += red[tid + s];
        __syncthreads();
    }
    const float inv = 1.0f / red[0];

    const float4* s4 = reinterpret_cast<const float4*>(scores);
    float4* o4 = reinterpret_cast<float4*>(out);
    #pragma unroll
    for (int i = tid; i < S / 4; i += 1024) {
        const float4 v = s4[i];
        o4[i] = make_float4(expf(v.x - M) * inv, expf(v.y - M) * inv,
                            expf(v.z - M) * inv, expf(v.w - M) * inv);
    }
}

extern "C" void kernel_launch(void* const* d_in, const int* in_sizes, int n_in,
                              void* d_out, int out_size, void* d_ws, size_t ws_size,
                              hipStream_t stream) {
    const float* hidden = (const float*)d_in[0];
    const float* enc    = (const float*)d_in[1];
    const float* W_lin  = (const float*)d_in[2];
    const float* b_lin  = (const float*)d_in[3];
    const float* W_attn = (const float*)d_in[4];
    const float* b_attn = (const float*)d_in[5];
    float* out = (float*)d_out;
    float* ws  = (float*)d_ws;

    float* scores   = ws;                        // 32768
    float* blockmax = ws + S;                    // 2048
    float* blocksum = ws + S + NB3;              // 2048
    float* h        = ws + S + 2 * NB3;          // 1024
    float* energy   = ws + S + 2 * NB3 + H;      // 1024

    gemv_kernel<<<H / 4, 256, 0, stream>>>(W_lin, hidden, b_lin, h);
    gemv_kernel<<<H / 4, 256, 0, stream>>>(W_attn, h, b_attn, energy);
    scores_kernel<<<NB3, 256, 0, stream>>>(enc, energy, scores, blockmax, blocksum);
    finalize_kernel<<<1, 1024, 0, stream>>>(scores, blockmax, blocksum, out);
}

// Round 6
// 212.050 us; speedup vs baseline: 2.7995x; 1.0041x over previous
//
#include <hip/hip_runtime.h>
#include <math.h>

#define H 1024
#define S 32768
#define NB3 2048                    // scores kernel blocks (4 waves, 4 rows/wave)
#define NFB 32                      // finalize blocks: 32*256 threads*float4 = 32768 elems

__device__ __forceinline__ float wave_reduce_sum(float v) {
    #pragma unroll
    for (int off = 32; off > 0; off >>= 1) v += __shfl_xor(v, off, 64);
    return v;
}

// y[row] = dot(W[row,:], x) + b[row].  One wave per row, 4 rows per block.
__global__ __launch_bounds__(256) void gemv_kernel(const float* __restrict__ W,
                                                   const float* __restrict__ x,
                                                   const float* __restrict__ b,
                                                   float* __restrict__ y) {
    const int tid = threadIdx.x;
    const int wave = tid >> 6, lane = tid & 63;
    const int row = blockIdx.x * 4 + wave;
    const float4* Wr = reinterpret_cast<const float4*>(W + (size_t)row * H);
    const float4* x4 = reinterpret_cast<const float4*>(x);

    float4 w[4], e[4];
    #pragma unroll
    for (int k = 0; k < 4; ++k) w[k] = Wr[k * 64 + lane];
    #pragma unroll
    for (int k = 0; k < 4; ++k) e[k] = x4[k * 64 + lane];

    float acc = 0.f;
    #pragma unroll
    for (int k = 0; k < 4; ++k)
        acc += w[k].x * e[k].x + w[k].y * e[k].y + w[k].z * e[k].z + w[k].w * e[k].w;
    acc = wave_reduce_sum(acc);
    if (lane == 0) y[row] = acc + b[row];
}

// scores[row] = enc[row,:] . energy  (4 rows/wave, all 16 loads in flight,
// energy in registers, reduces deferred and packed).
__global__ __launch_bounds__(256) void scores_kernel(
    const float* __restrict__ enc,
    const float* __restrict__ energy,
    float* __restrict__ scores,      // [S]   ws
    float* __restrict__ blockmax,    // [NB3] ws
    float* __restrict__ blocksum)    // [NB3] ws
{
    __shared__ float redm[4], reds[4];
    const int tid = threadIdx.x;
    const int wave = tid >> 6, lane = tid & 63;
    const int bid  = blockIdx.x;

    const float4* e4 = reinterpret_cast<const float4*>(energy);
    float4 e[4];
    #pragma unroll
    for (int k = 0; k < 4; ++k) e[k] = e4[k * 64 + lane];   // L2/L3-hit

    const int wrow0 = (bid * 4 + wave) * 4;                 // 4 contiguous rows
    const float4* Er = reinterpret_cast<const float4*>(enc + (size_t)wrow0 * H);

    // issue all 16 global loads (16 KB contiguous per wave) before any math
    float4 w[4][4];
    #pragma unroll
    for (int p = 0; p < 4; ++p)
        #pragma unroll
        for (int k = 0; k < 4; ++k)
            w[p][k] = Er[p * 256 + k * 64 + lane];

    float acc[4];
    #pragma unroll
    for (int p = 0; p < 4; ++p) {
        float a = 0.f;
        #pragma unroll
        for (int k = 0; k < 4; ++k)
            a += w[p][k].x * e[k].x + w[p][k].y * e[k].y +
                 w[p][k].z * e[k].z + w[p][k].w * e[k].w;
        acc[p] = a;
    }

    // packed butterfly: 4 rows reduced simultaneously (one 6-step chain)
    #pragma unroll
    for (int off = 32; off > 0; off >>= 1) {
        #pragma unroll
        for (int p = 0; p < 4; ++p) acc[p] += __shfl_xor(acc[p], off, 64);
    }

    const float wmax = fmaxf(fmaxf(acc[0], acc[1]), fmaxf(acc[2], acc[3]));
    if (lane == 0) {
        reinterpret_cast<float4*>(scores)[bid * 4 + wave] =
            make_float4(acc[0], acc[1], acc[2], acc[3]);
        redm[wave] = wmax;
    }
    __syncthreads();
    const float bm = fmaxf(fmaxf(redm[0], redm[1]), fmaxf(redm[2], redm[3]));

    float wsum = 0.f;                        // wave-uniform
    #pragma unroll
    for (int p = 0; p < 4; ++p) wsum += expf(acc[p] - bm);
    if (lane == 0) reds[wave] = wsum;
    __syncthreads();
    if (tid == 0) {
        blockmax[bid] = bm;
        blocksum[bid] = reds[0] + reds[1] + reds[2] + reds[3];
    }
}

// NFB blocks: every block redundantly reduces the 2048 {max,sum} pairs
// (16 KB, L2-resident), then normalizes its slice: exactly one float4/thread.
__global__ __launch_bounds__(256) void finalize_kernel(
    const float* __restrict__ scores,
    const float* __restrict__ blockmax,
    const float* __restrict__ blocksum,
    float* __restrict__ out)
{
    __shared__ float redm[4], reds[4];
    const int tid = threadIdx.x;
    const int wave = tid >> 6, lane = tid & 63;

    float m = -INFINITY;
    #pragma unroll
    for (int i = 0; i < NB3 / 256; ++i) m = fmaxf(m, blockmax[tid + i * 256]);
    #pragma unroll
    for (int off = 32; off > 0; off >>= 1) m = fmaxf(m, __shfl_xor(m, off, 64));
    if (lane == 0) redm[wave] = m;
    __syncthreads();
    const float M = fmaxf(fmaxf(redm[0], redm[1]), fmaxf(redm[2], redm[3]));

    float t = 0.f;
    #pragma unroll
    for (int i = 0; i < NB3 / 256; ++i) {
        const int b = tid + i * 256;
        t += blocksum[b] * expf(blockmax[b] - M);
    }
    t = wave_reduce_sum(t);
    if (lane == 0) reds[wave] = t;
    __syncthreads();
    const float inv = 1.0f / (reds[0] + reds[1] + reds[2] + reds[3]);

    // normalize: one float4 per thread (32 blocks x 256 threads x 4 = 32768)
    const int idx = blockIdx.x * 256 + tid;
    const float4 v = reinterpret_cast<const float4*>(scores)[idx];
    reinterpret_cast<float4*>(out)[idx] =
        make_float4(expf(v.x - M) * inv, expf(v.y - M) * inv,
                    expf(v.z - M) * inv, expf(v.w - M) * inv);
}

extern "C" void kernel_launch(void* const* d_in, const int* in_sizes, int n_in,
                              void* d_out, int out_size, void* d_ws, size_t ws_size,
                              hipStream_t stream) {
    const float* hidden = (const float*)d_in[0];
    const float* enc    = (const float*)d_in[1];
    const float* W_lin  = (const float*)d_in[2];
    const float* b_lin  = (const float*)d_in[3];
    const float* W_attn = (const float*)d_in[4];
    const float* b_attn = (const float*)d_in[5];
    float* out = (float*)d_out;
    float* ws  = (float*)d_ws;

    float* scores   = ws;                        // 32768
    float* blockmax = ws + S;                    // 2048
    float* blocksum = ws + S + NB3;              // 2048
    float* h        = ws + S + 2 * NB3;          // 1024
    float* energy   = ws + S + 2 * NB3 + H;      // 1024

    gemv_kernel<<<H / 4, 256, 0, stream>>>(W_lin, hidden, b_lin, h);
    gemv_kernel<<<H / 4, 256, 0, stream>>>(W_attn, h, b_attn, energy);
    scores_kernel<<<NB3, 256, 0, stream>>>(enc, energy, scores, blockmax, blocksum);
    finalize_kernel<<<NFB, 256, 0, stream>>>(scores, blockmax, blocksum, out);
}